// Round 4
// baseline (281.973 us; speedup 1.0000x reference)
//
#include <hip/hip_runtime.h>
#include <hip/hip_bf16.h>

// Problem constants (fixed by reference)
#define Bn 16
#define Tn 64
#define Nn 256
#define Kn 8
#define dn 8
#define Dn 64
#define TDn 128   // 2*D

typedef __bf16 bf16x8 __attribute__((ext_vector_type(8)));
typedef __bf16 bf16x4 __attribute__((ext_vector_type(4)));
typedef __bf16 bf16x2 __attribute__((ext_vector_type(2)));
typedef float  f32x4  __attribute__((ext_vector_type(4)));

#if __has_builtin(__builtin_amdgcn_exp2f)
#define EXP2F(x) __builtin_amdgcn_exp2f(x)
#else
#define EXP2F(x) exp2f(x)
#endif

#if __has_builtin(__builtin_amdgcn_rcpf)
#define RCPF(x) __builtin_amdgcn_rcpf(x)
#else
#define RCPF(x) (1.0f / (x))
#endif

// tanh-form GELU via native exp2 + rcp (~10 VALU ops vs ~60 for libm erff).
__device__ __forceinline__ float geluf(float x) {
    const float x2 = x * x;
    const float v = x * fmaf(0.10294342f, x2, 2.30220920f);   // 2*log2e*0.79788456*(x+0.044715x^3)
    const float w = EXP2F(-fabsf(v));
    const float r = RCPF(1.0f + w);
    const float t = (1.0f - w) * r;                            // tanh(|u|)
    return fmaf(0.5f * fabsf(x), t, 0.5f * x);
}

__device__ __forceinline__ bf16x8 bzero8() {
    bf16x8 z;
    #pragma unroll
    for (int e = 0; e < 8; ++e) z[e] = (__bf16)0.0f;
    return z;
}
__device__ __forceinline__ bf16x4 bzero4() {
    bf16x4 z;
    #pragma unroll
    for (int e = 0; e < 4; ++e) z[e] = (__bf16)0.0f;
    return z;
}

// ---- Kernel 1: convert all weights fp32 -> bf16 into d_ws ----
// ws layout (bf16): [0,24576) Wqkv rows 0-63=W12,64-127=W13,128-191=W14 (row=128 k)
//                   [24576,28672) W15 [64][64]; [28672,32768) W16 [64][64]
__global__ void convert_weights(const float* __restrict__ W12, const float* __restrict__ W13,
                                const float* __restrict__ W14, const float* __restrict__ W15,
                                const float* __restrict__ W16, __bf16* __restrict__ ws)
{
    const int i = blockIdx.x * 256 + threadIdx.x;   // 0..32767
    float v;
    if      (i < 8192)  v = W12[i];
    else if (i < 16384) v = W13[i - 8192];
    else if (i < 24576) v = W14[i - 16384];
    else if (i < 28672) v = W15[i - 24576];
    else                v = W16[i - 28672];
    ws[i] = (__bf16)v;
}

// ---- MFMA attention tile: S^T = K.Q^T for tq-tile J, softmax rows, out^T = V^T.P^T ----
// C/D layout (harness-verified): col = lane&15, row = (lane>>4)*4 + r.
// S^T tile (i,J): lane cl = tq (within tile J), reg (quad,r) = tk (within tile i).
// Ps is HALF-SIZED [16][40] (32 payload cols + pad): tile-pairs {0,1} then {2,3} are
// staged sequentially between the two PV MFMAs (same-wave DS ops are in-order).
template <int J>
__device__ __forceinline__ void attn_tile(__bf16 (*qs)[72], __bf16 (*Ps)[40],
                                          bf16x8 kf0, bf16x8 kf1, bf16x8 kf2, bf16x8 kf3,
                                          bf16x8 vf0, bf16x8 vf1,
                                          int hc, int cl, int quad, int kb)
{
    // Q B-frag for tq-tile J: lane cl reads Q[16J+cl][d 0..7] (quad 0), quads 1-3 zero-pad K.
    bf16x8 qf = bzero8();
    if (quad == 0) qf = *reinterpret_cast<const bf16x8*>(&qs[16 * J + cl][hc]);

    const f32x4 zc = {0.f, 0.f, 0.f, 0.f};
    f32x4 st[4];
    st[0] = __builtin_amdgcn_mfma_f32_16x16x32_bf16(kf0, qf, zc, 0, 0, 0);
    if constexpr (J >= 1) st[1] = __builtin_amdgcn_mfma_f32_16x16x32_bf16(kf1, qf, zc, 0, 0, 0);
    if constexpr (J >= 2) st[2] = __builtin_amdgcn_mfma_f32_16x16x32_bf16(kf2, qf, zc, 0, 0, 0);
    if constexpr (J >= 3) st[3] = __builtin_amdgcn_mfma_f32_16x16x32_bf16(kf3, qf, zc, 0, 0, 0);

    // Causal mask inside the diagonal tile (i == J): tk-in-tile = 4*quad+r, tq-in-tile = cl.
    #pragma unroll
    for (int r = 0; r < 4; ++r)
        st[J][r] = (4 * quad + r > cl) ? -3.0e38f : st[J][r];

    // Row max: own regs, then cross-quad via shfl_xor 16/32.
    float mx = -3.0e38f;
    #pragma unroll
    for (int i = 0; i <= J; ++i) {
        #pragma unroll
        for (int r = 0; r < 4; ++r) mx = fmaxf(mx, st[i][r]);
    }
    mx = fmaxf(mx, __shfl_xor(mx, 16));
    mx = fmaxf(mx, __shfl_xor(mx, 32));

    // exp2 (q pre-scaled by 1/sqrt(8)*log2e in phase 2) + row sum.
    float sum = 0.f;
    #pragma unroll
    for (int i = 0; i <= J; ++i) {
        #pragma unroll
        for (int r = 0; r < 4; ++r) {
            const float p = EXP2F(st[i][r] - mx);
            st[i][r] = p;
            sum += p;
        }
    }
    sum += __shfl_xor(sum, 16);
    sum += __shfl_xor(sum, 32);

    f32x4 o = {0.f, 0.f, 0.f, 0.f};

    // ---- half 0: stage tiles {0,1} into Ps cols [0,32), then PV MFMA over tk 0..31 ----
    {
        bf16x4 pk0;
        #pragma unroll
        for (int r = 0; r < 4; ++r) pk0[r] = (__bf16)st[0][r];
        *reinterpret_cast<bf16x4*>(&Ps[cl][4 * quad]) = pk0;
        if constexpr (J >= 1) {
            bf16x4 pk1;
            #pragma unroll
            for (int r = 0; r < 4; ++r) pk1[r] = (__bf16)st[1][r];
            *reinterpret_cast<bf16x4*>(&Ps[cl][16 + 4 * quad]) = pk1;
        } else {
            *reinterpret_cast<bf16x4*>(&Ps[cl][16 + 4 * quad]) = bzero4();
        }
        const bf16x8 pf = *reinterpret_cast<const bf16x8*>(&Ps[cl][kb]);
        o = __builtin_amdgcn_mfma_f32_16x16x32_bf16(vf0, pf, o, 0, 0, 0);
    }
    // ---- half 1: stage tiles {2,3}, PV MFMA over tk 32..63 (program order keeps the
    //      overwrite after the half-0 read; same-wave DS ops are in-order) ----
    if constexpr (J >= 2) {
        bf16x4 pk2;
        #pragma unroll
        for (int r = 0; r < 4; ++r) pk2[r] = (__bf16)st[2][r];
        *reinterpret_cast<bf16x4*>(&Ps[cl][4 * quad]) = pk2;
        if constexpr (J >= 3) {
            bf16x4 pk3;
            #pragma unroll
            for (int r = 0; r < 4; ++r) pk3[r] = (__bf16)st[3][r];
            *reinterpret_cast<bf16x4*>(&Ps[cl][16 + 4 * quad]) = pk3;
        } else {
            *reinterpret_cast<bf16x4*>(&Ps[cl][16 + 4 * quad]) = bzero4();
        }
        const bf16x8 pf = *reinterpret_cast<const bf16x8*>(&Ps[cl][kb]);
        o = __builtin_amdgcn_mfma_f32_16x16x32_bf16(vf1, pf, o, 0, 0, 0);
    }

    // out^T C-layout: col = cl = tq, row = 4*quad+r = d (d<8 -> quads 0,1 only).
    const float inv = RCPF(sum);   // sum >= 1 (diagonal term exp2(0)=1)
    if (quad < 2) {
        bf16x4 ov;
        #pragma unroll
        for (int r = 0; r < 4; ++r) ov[r] = (__bf16)(o[r] * inv);
        *reinterpret_cast<bf16x4*>(&qs[16 * J + cl][hc + 4 * quad]) = ov;
    }
}

// ---- Kernel 2: fused block per (b,n); 256 threads = 4 waves ----
// LDS 32,768 B -> 5 blocks/CU (20 waves).
// Regions: [0,9216)      vt[64][72] bf16 (V transposed, row = h*8+d)
//          [9216,18432)  qs[64][72]  (q in phase 2-3, attention output after phase 3)
//          [18432,27648) ks[64][72]  (k in phase 2-3, MLP hidden in phase 4)
//          [27648,32768) Ps half-slices (+wv*1280, [16][40] bf16 per wave)
// Phases 2/4a/4b use SWAPPED MFMA operands (D = W.H^T): C rows = feats, cols = t ->
// each lane owns 4 consecutive feats at one t -> all epilogues are b64/dwordx4 stores.
__global__ __launch_bounds__(256, 5)
void tam_fused(const float* __restrict__ X,
               const float* __restrict__ STE,
               const float* __restrict__ b12, const float* __restrict__ b13,
               const float* __restrict__ b14, const float* __restrict__ b15,
               const float* __restrict__ b16,
               const __bf16* __restrict__ Wb,   // converted weights in ws
               float* __restrict__ Out)
{
    __shared__ __align__(16) char smem[32768];
    __bf16 (*vt)[72] = reinterpret_cast<__bf16 (*)[72]>(smem);           // [64][72]: V^T
    __bf16 (*qs)[72] = reinterpret_cast<__bf16 (*)[72]>(smem + 9216);    // [64][72]
    __bf16 (*ks)[72] = reinterpret_cast<__bf16 (*)[72]>(smem + 18432);   // [64][72]

    const int bn   = blockIdx.x;
    const int b    = bn >> 8;     // / Nn
    const int n    = bn & 255;    // % Nn
    const int tid  = threadIdx.x;
    const int lane = tid & 63;
    const int wv   = __builtin_amdgcn_readfirstlane(tid >> 6);
    const int cl   = lane & 15;          // MFMA col-in-tile / A-row-in-tile
    const int quad = lane >> 4;
    const int kb   = quad * 8;           // MFMA k-offset (quad*8)
    const int m0   = wv * 16;            // this wave's row-tile

    __bf16 (*Ps)[40] = reinterpret_cast<__bf16 (*)[40]>(smem + 27648 + wv * 1280);

    const __bf16* Wqkv = Wb;             // [192][128]
    const __bf16* W15b = Wb + 24576;     // [64][64]
    const __bf16* W16b = Wb + 28672;     // [64][64]

    // ---------------- Phase 2: qkv = gelu(H @ Wqkv^T + b) via MFMA ----------------
    // A-frags (H rows) direct from global; q/k use swapped operands (D[feat][t]),
    // v unswapped (D[t][feat]) since vt wants the transposed layout anyway.
    // q written pre-scaled by 1/sqrt(8)*log2(e) (attention uses exp2 directly).
    {
        bf16x8 af[4];
        {
            const int t = m0 + cl;
            const size_t rb = (((size_t)b * Tn + t) * Nn + n) * (size_t)Dn;
            const float4* Xr = reinterpret_cast<const float4*>(X + rb);
            const float4* Sr = reinterpret_cast<const float4*>(STE + rb);
            #pragma unroll
            for (int kk = 0; kk < 4; ++kk) {
                const float4* src = (kk < 2) ? Xr : Sr;
                const int fi = (kk & 1) * 8 + quad * 2;
                const float4 f0 = src[fi];
                const float4 f1 = src[fi + 1];
                bf16x8 a;
                a[0] = (__bf16)f0.x; a[1] = (__bf16)f0.y;
                a[2] = (__bf16)f0.z; a[3] = (__bf16)f0.w;
                a[4] = (__bf16)f1.x; a[5] = (__bf16)f1.y;
                a[6] = (__bf16)f1.z; a[7] = (__bf16)f1.w;
                af[kk] = a;
            }
        }

        #pragma unroll
        for (int nt = 0; nt < 12; ++nt) {
            const int n0 = nt * 16;
            f32x4 acc = {0.f, 0.f, 0.f, 0.f};
            if (nt < 8) {
                // swapped: D = W.H^T -> row = feat n0+4q+r, col = t m0+cl
                #pragma unroll
                for (int kk = 0; kk < 4; ++kk) {
                    const bf16x8 bf = *reinterpret_cast<const bf16x8*>(
                        &Wqkv[(n0 + cl) * TDn + kk * 32 + kb]);
                    acc = __builtin_amdgcn_mfma_f32_16x16x32_bf16(bf, af[kk], acc, 0, 0, 0);
                }
                if (nt < 4) {
                    const float4 bs = *reinterpret_cast<const float4*>(&b12[n0 + 4 * quad]);
                    bf16x4 pk;
                    pk[0] = (__bf16)(geluf(acc[0] + bs.x) * 0.51006951f);
                    pk[1] = (__bf16)(geluf(acc[1] + bs.y) * 0.51006951f);
                    pk[2] = (__bf16)(geluf(acc[2] + bs.z) * 0.51006951f);
                    pk[3] = (__bf16)(geluf(acc[3] + bs.w) * 0.51006951f);
                    *reinterpret_cast<bf16x4*>(&qs[m0 + cl][n0 + 4 * quad]) = pk;
                } else {
                    const float4 bs = *reinterpret_cast<const float4*>(&b13[n0 - 64 + 4 * quad]);
                    bf16x4 pk;
                    pk[0] = (__bf16)geluf(acc[0] + bs.x);
                    pk[1] = (__bf16)geluf(acc[1] + bs.y);
                    pk[2] = (__bf16)geluf(acc[2] + bs.z);
                    pk[3] = (__bf16)geluf(acc[3] + bs.w);
                    *reinterpret_cast<bf16x4*>(&ks[m0 + cl][n0 - 64 + 4 * quad]) = pk;
                }
            } else {
                // unswapped: D = H.W^T -> row = t m0+4q+r, col = feat n0-128+cl
                #pragma unroll
                for (int kk = 0; kk < 4; ++kk) {
                    const bf16x8 bf = *reinterpret_cast<const bf16x8*>(
                        &Wqkv[(n0 + cl) * TDn + kk * 32 + kb]);
                    acc = __builtin_amdgcn_mfma_f32_16x16x32_bf16(af[kk], bf, acc, 0, 0, 0);
                }
                const float bias = b14[n0 - 128 + cl];
                bf16x4 pv;
                #pragma unroll
                for (int r = 0; r < 4; ++r) pv[r] = (__bf16)geluf(acc[r] + bias);
                // col = h*8+d; rows m0+4q..+3 are consecutive t -> contiguous in vt[col][t]
                *reinterpret_cast<bf16x4*>(&vt[n0 - 128 + cl][m0 + 4 * quad]) = pv;
            }
        }
    }
    __syncthreads();

    // ---------------- Phase 3: MFMA attention (S^T orientation), 2 heads per wave ----------
    // Wave wv owns heads {2wv, 2wv+1} = qs/ks/vt columns [16wv,16wv+16): column-disjoint
    // across waves; Ps is wave-private -> no internal barriers.
    {
        #pragma unroll
        for (int hh = 0; hh < 2; ++hh) {
            const int h  = 2 * wv + hh;
            const int hc = 8 * h;

            // K A-frags: lane cl = tk row, quad 0 holds d 0..7, quads 1-3 zero-pad K=32.
            bf16x8 kf0 = bzero8(), kf1 = bzero8(), kf2 = bzero8(), kf3 = bzero8();
            if (quad == 0) {
                kf0 = *reinterpret_cast<const bf16x8*>(&ks[ 0 + cl][hc]);
                kf1 = *reinterpret_cast<const bf16x8*>(&ks[16 + cl][hc]);
                kf2 = *reinterpret_cast<const bf16x8*>(&ks[32 + cl][hc]);
                kf3 = *reinterpret_cast<const bf16x8*>(&ks[48 + cl][hc]);
            }
            // V^T A-frags: lane cl = d row (cl<8 real), k = tk = kk*32+kb.
            bf16x8 vf0 = bzero8(), vf1 = bzero8();
            if (cl < 8) {
                vf0 = *reinterpret_cast<const bf16x8*>(&vt[hc + cl][kb]);
                vf1 = *reinterpret_cast<const bf16x8*>(&vt[hc + cl][32 + kb]);
            }

            attn_tile<0>(qs, Ps, kf0, kf1, kf2, kf3, vf0, vf1, hc, cl, quad, kb);
            attn_tile<1>(qs, Ps, kf0, kf1, kf2, kf3, vf0, vf1, hc, cl, quad, kb);
            attn_tile<2>(qs, Ps, kf0, kf1, kf2, kf3, vf0, vf1, hc, cl, quad, kb);
            attn_tile<3>(qs, Ps, kf0, kf1, kf2, kf3, vf0, vf1, hc, cl, quad, kb);
        }
    }
    __syncthreads();

    // ---------------- Phase 4a: hidden = gelu(attn_out @ W15^T + b15) -> ks (swapped) -------
    // D[feat=n0+4q+r][t=m0+cl]: b64 write per tile. B-frag = attn_out rows (qs).
    {
        const bf16x8 h0 = *reinterpret_cast<const bf16x8*>(&qs[m0 + cl][kb]);
        const bf16x8 h1 = *reinterpret_cast<const bf16x8*>(&qs[m0 + cl][32 + kb]);
        #pragma unroll
        for (int nt = 0; nt < 4; ++nt) {
            const int n0 = nt * 16;
            f32x4 acc = {0.f, 0.f, 0.f, 0.f};
            const bf16x8 w0 = *reinterpret_cast<const bf16x8*>(&W15b[(n0 + cl) * Dn + kb]);
            acc = __builtin_amdgcn_mfma_f32_16x16x32_bf16(w0, h0, acc, 0, 0, 0);
            const bf16x8 w1 = *reinterpret_cast<const bf16x8*>(&W15b[(n0 + cl) * Dn + 32 + kb]);
            acc = __builtin_amdgcn_mfma_f32_16x16x32_bf16(w1, h1, acc, 0, 0, 0);
            const float4 bs = *reinterpret_cast<const float4*>(&b15[n0 + 4 * quad]);
            bf16x4 pk;
            pk[0] = (__bf16)geluf(acc[0] + bs.x);
            pk[1] = (__bf16)geluf(acc[1] + bs.y);
            pk[2] = (__bf16)geluf(acc[2] + bs.z);
            pk[3] = (__bf16)geluf(acc[3] + bs.w);
            *reinterpret_cast<bf16x4*>(&ks[m0 + cl][n0 + 4 * quad]) = pk;
        }
    }
    // No barrier: phase 4b reads only this wave's 16 rows of ks (same-wave DS in-order).

    // ---------------- Phase 4b: out = hidden @ W16^T + b16 -> global fp32 (swapped) ---------
    // D[feat=n0+4q+r][t=m0+cl]: one dwordx4 global store per tile.
    {
        const bf16x8 h0 = *reinterpret_cast<const bf16x8*>(&ks[m0 + cl][kb]);
        const bf16x8 h1 = *reinterpret_cast<const bf16x8*>(&ks[m0 + cl][32 + kb]);
        const size_t ob = (((size_t)(b * Tn + m0 + cl)) * Nn + n) * (size_t)Dn;
        #pragma unroll
        for (int nt = 0; nt < 4; ++nt) {
            const int n0 = nt * 16;
            f32x4 acc = {0.f, 0.f, 0.f, 0.f};
            const bf16x8 w0 = *reinterpret_cast<const bf16x8*>(&W16b[(n0 + cl) * Dn + kb]);
            acc = __builtin_amdgcn_mfma_f32_16x16x32_bf16(w0, h0, acc, 0, 0, 0);
            const bf16x8 w1 = *reinterpret_cast<const bf16x8*>(&W16b[(n0 + cl) * Dn + 32 + kb]);
            acc = __builtin_amdgcn_mfma_f32_16x16x32_bf16(w1, h1, acc, 0, 0, 0);
            const float4 bs = *reinterpret_cast<const float4*>(&b16[n0 + 4 * quad]);
            float4 ov;
            ov.x = acc[0] + bs.x;
            ov.y = acc[1] + bs.y;
            ov.z = acc[2] + bs.z;
            ov.w = acc[3] + bs.w;
            *reinterpret_cast<float4*>(&Out[ob + n0 + 4 * quad]) = ov;
        }
    }
}

extern "C" void kernel_launch(void* const* d_in, const int* in_sizes, int n_in,
                              void* d_out, int out_size, void* d_ws, size_t ws_size,
                              hipStream_t stream)
{
    (void)in_sizes; (void)n_in; (void)out_size; (void)ws_size;
    const float* X   = (const float*)d_in[0];
    const float* STE = (const float*)d_in[1];
    const float* W12 = (const float*)d_in[2];
    const float* b12 = (const float*)d_in[3];
    const float* W13 = (const float*)d_in[4];
    const float* b13 = (const float*)d_in[5];
    const float* W14 = (const float*)d_in[6];
    const float* b14 = (const float*)d_in[7];
    const float* W15 = (const float*)d_in[8];
    const float* b15 = (const float*)d_in[9];
    const float* W16 = (const float*)d_in[10];
    const float* b16 = (const float*)d_in[11];
    float* Out = (float*)d_out;
    __bf16* ws = (__bf16*)d_ws;   // needs 65,536 B

    hipLaunchKernelGGL(convert_weights, dim3(128), dim3(256), 0, stream,
                       W12, W13, W14, W15, W16, ws);
    hipLaunchKernelGGL(tam_fused, dim3(Bn * Nn), dim3(256), 0, stream,
                       X, STE, b12, b13, b14, b15, b16, ws, Out);
}

// Round 5
// 281.949 us; speedup vs baseline: 1.0001x; 1.0001x over previous
//
#include <hip/hip_runtime.h>
#include <hip/hip_bf16.h>

// Problem constants (fixed by reference)
#define Bn 16
#define Tn 64
#define Nn 256
#define Kn 8
#define dn 8
#define Dn 64
#define TDn 128   // 2*D

typedef __bf16 bf16x8 __attribute__((ext_vector_type(8)));
typedef __bf16 bf16x4 __attribute__((ext_vector_type(4)));
typedef __bf16 bf16x2 __attribute__((ext_vector_type(2)));
typedef float  f32x4  __attribute__((ext_vector_type(4)));
typedef float  f32x16 __attribute__((ext_vector_type(16)));

#if __has_builtin(__builtin_amdgcn_exp2f)
#define EXP2F(x) __builtin_amdgcn_exp2f(x)
#else
#define EXP2F(x) exp2f(x)
#endif

#if __has_builtin(__builtin_amdgcn_rcpf)
#define RCPF(x) __builtin_amdgcn_rcpf(x)
#else
#define RCPF(x) (1.0f / (x))
#endif

// tanh-form GELU via native exp2 + rcp (~10 VALU ops vs ~60 for libm erff).
__device__ __forceinline__ float geluf(float x) {
    const float x2 = x * x;
    const float v = x * fmaf(0.10294342f, x2, 2.30220920f);   // 2*log2e*0.79788456*(x+0.044715x^3)
    const float w = EXP2F(-fabsf(v));
    const float r = RCPF(1.0f + w);
    const float t = (1.0f - w) * r;                            // tanh(|u|)
    return fmaf(0.5f * fabsf(x), t, 0.5f * x);
}

__device__ __forceinline__ bf16x8 bzero8() {
    bf16x8 z;
    #pragma unroll
    for (int e = 0; e < 8; ++e) z[e] = (__bf16)0.0f;
    return z;
}

// ---- Kernel 1: convert all weights fp32 -> bf16 into d_ws ----
// ws layout (bf16): [0,24576) Wqkv rows 0-63=W12,64-127=W13,128-191=W14 (row=128 k)
//                   [24576,28672) W15 [64][64]; [28672,32768) W16 [64][64]
__global__ void convert_weights(const float* __restrict__ W12, const float* __restrict__ W13,
                                const float* __restrict__ W14, const float* __restrict__ W15,
                                const float* __restrict__ W16, __bf16* __restrict__ ws)
{
    const int i = blockIdx.x * 256 + threadIdx.x;   // 0..32767
    float v;
    if      (i < 8192)  v = W12[i];
    else if (i < 16384) v = W13[i - 8192];
    else if (i < 24576) v = W14[i - 16384];
    else if (i < 28672) v = W15[i - 24576];
    else                v = W16[i - 28672];
    ws[i] = (__bf16)v;
}

// ---- Kernel 2: fused block per (b,n); 256 threads = 4 waves ----
// LDS 27,648 B -> 5 blocks/CU (20 waves) with real headroom (138 KB of 160).
// Regions: [0,9216)      vt[64][72] bf16 (V transposed, row = h*8+d)
//          [9216,18432)  qs[64][72]  (q in phase 2-3, attention output after phase 3)
//          [18432,27648) ks[64][72]  (k in phase 2-3, MLP hidden in phase 4)
// Phases 2/4a/4b use SWAPPED MFMA operands (D = W.H^T) so epilogues are b64/dwordx4 stores.
// Phase 3 uses 32x32x16 MFMAs with the P matrix kept ENTIRELY in registers:
// S^T C-layout (col=tq=lane&31, regs=tk) is one lane^32 swap away from the PV B-frag
// layout, so 4 shfl_xor(32) + 4 selects per 16-tk chunk replace the LDS P round-trip.
__global__ __launch_bounds__(256, 5)
void tam_fused(const float* __restrict__ X,
               const float* __restrict__ STE,
               const float* __restrict__ b12, const float* __restrict__ b13,
               const float* __restrict__ b14, const float* __restrict__ b15,
               const float* __restrict__ b16,
               const __bf16* __restrict__ Wb,   // converted weights in ws
               float* __restrict__ Out)
{
    __shared__ __align__(16) char smem[27648];
    __bf16 (*vt)[72] = reinterpret_cast<__bf16 (*)[72]>(smem);           // [64][72]: V^T
    __bf16 (*qs)[72] = reinterpret_cast<__bf16 (*)[72]>(smem + 9216);    // [64][72]
    __bf16 (*ks)[72] = reinterpret_cast<__bf16 (*)[72]>(smem + 18432);   // [64][72]

    const int bn   = blockIdx.x;
    const int b    = bn >> 8;     // / Nn
    const int n    = bn & 255;    // % Nn
    const int tid  = threadIdx.x;
    const int lane = tid & 63;
    const int wv   = __builtin_amdgcn_readfirstlane(tid >> 6);
    const int cl   = lane & 15;          // 16x16 MFMA col-in-tile / A-row-in-tile
    const int quad = lane >> 4;
    const int kb   = quad * 8;           // 16x16 MFMA k-offset
    const int m0   = wv * 16;            // this wave's row-tile

    const __bf16* Wqkv = Wb;             // [192][128]
    const __bf16* W15b = Wb + 24576;     // [64][64]
    const __bf16* W16b = Wb + 28672;     // [64][64]

    // ---------------- Phase 2: qkv = gelu(H @ Wqkv^T + b) via MFMA (16x16x32) ----------------
    // A-frags (H rows) direct from global; q/k use swapped operands (D[feat][t]),
    // v unswapped (D[t][feat]) since vt wants the transposed layout anyway.
    // q written pre-scaled by 1/sqrt(8)*log2(e) (attention uses exp2 directly).
    {
        bf16x8 af[4];
        {
            const int t = m0 + cl;
            const size_t rb = (((size_t)b * Tn + t) * Nn + n) * (size_t)Dn;
            const float4* Xr = reinterpret_cast<const float4*>(X + rb);
            const float4* Sr = reinterpret_cast<const float4*>(STE + rb);
            #pragma unroll
            for (int kk = 0; kk < 4; ++kk) {
                const float4* src = (kk < 2) ? Xr : Sr;
                const int fi = (kk & 1) * 8 + quad * 2;
                const float4 f0 = src[fi];
                const float4 f1 = src[fi + 1];
                bf16x8 a;
                a[0] = (__bf16)f0.x; a[1] = (__bf16)f0.y;
                a[2] = (__bf16)f0.z; a[3] = (__bf16)f0.w;
                a[4] = (__bf16)f1.x; a[5] = (__bf16)f1.y;
                a[6] = (__bf16)f1.z; a[7] = (__bf16)f1.w;
                af[kk] = a;
            }
        }

        #pragma unroll
        for (int nt = 0; nt < 12; ++nt) {
            const int n0 = nt * 16;
            f32x4 acc = {0.f, 0.f, 0.f, 0.f};
            if (nt < 8) {
                // swapped: D = W.H^T -> row = feat n0+4q+r, col = t m0+cl
                #pragma unroll
                for (int kk = 0; kk < 4; ++kk) {
                    const bf16x8 bf = *reinterpret_cast<const bf16x8*>(
                        &Wqkv[(n0 + cl) * TDn + kk * 32 + kb]);
                    acc = __builtin_amdgcn_mfma_f32_16x16x32_bf16(bf, af[kk], acc, 0, 0, 0);
                }
                if (nt < 4) {
                    const float4 bs = *reinterpret_cast<const float4*>(&b12[n0 + 4 * quad]);
                    bf16x4 pk;
                    pk[0] = (__bf16)(geluf(acc[0] + bs.x) * 0.51006951f);
                    pk[1] = (__bf16)(geluf(acc[1] + bs.y) * 0.51006951f);
                    pk[2] = (__bf16)(geluf(acc[2] + bs.z) * 0.51006951f);
                    pk[3] = (__bf16)(geluf(acc[3] + bs.w) * 0.51006951f);
                    *reinterpret_cast<bf16x4*>(&qs[m0 + cl][n0 + 4 * quad]) = pk;
                } else {
                    const float4 bs = *reinterpret_cast<const float4*>(&b13[n0 - 64 + 4 * quad]);
                    bf16x4 pk;
                    pk[0] = (__bf16)geluf(acc[0] + bs.x);
                    pk[1] = (__bf16)geluf(acc[1] + bs.y);
                    pk[2] = (__bf16)geluf(acc[2] + bs.z);
                    pk[3] = (__bf16)geluf(acc[3] + bs.w);
                    *reinterpret_cast<bf16x4*>(&ks[m0 + cl][n0 - 64 + 4 * quad]) = pk;
                }
            } else {
                // unswapped: D = H.W^T -> row = t m0+4q+r, col = feat n0-128+cl
                #pragma unroll
                for (int kk = 0; kk < 4; ++kk) {
                    const bf16x8 bf = *reinterpret_cast<const bf16x8*>(
                        &Wqkv[(n0 + cl) * TDn + kk * 32 + kb]);
                    acc = __builtin_amdgcn_mfma_f32_16x16x32_bf16(af[kk], bf, acc, 0, 0, 0);
                }
                const float bias = b14[n0 - 128 + cl];
                bf16x4 pv;
                #pragma unroll
                for (int r = 0; r < 4; ++r) pv[r] = (__bf16)geluf(acc[r] + bias);
                // col = h*8+d; rows m0+4q..+3 are consecutive t -> contiguous in vt[col][t]
                *reinterpret_cast<bf16x4*>(&vt[n0 - 128 + cl][m0 + 4 * quad]) = pv;
            }
        }
    }
    __syncthreads();

    // ---------------- Phase 3: 32x32x16 MFMA attention, P fully in registers ----------
    // Wave wv owns heads {2wv, 2wv+1} = qs/ks/vt columns [16wv,16wv+16): column-disjoint
    // across waves -> no internal barriers. Per head, causal 64x64 needs 3 of 4 32x32
    // tiles: (tq0,tk0) tri, (tq1,tk0) full, (tq1,tk1) tri.
    // 32x32x16 frag layouts (analog of the harness-verified 16x16x32 patterns):
    //   A: row = lane&31, k = (lane>>5)*8 + e;  B: col = lane&31, k = (lane>>5)*8 + e
    //   C: col = lane&31, row = (reg&3) + 8*(reg>>2) + 4*(lane>>5)   [guide-verified]
    {
        const int half = lane >> 5;
        const int l31  = lane & 31;

        for (int hh = 0; hh < 2; ++hh) {
            const int hc = 8 * (2 * wv + hh);

            // K A-frags (k = d 0..7 in half 0; half 1 zero-pads K=16 to d=8)
            bf16x8 kA0 = bzero8(), kA1 = bzero8(), qB0 = bzero8(), qB1 = bzero8();
            if (half == 0) {
                kA0 = *reinterpret_cast<const bf16x8*>(&ks[ 0 + l31][hc]);
                kA1 = *reinterpret_cast<const bf16x8*>(&ks[32 + l31][hc]);
                qB0 = *reinterpret_cast<const bf16x8*>(&qs[ 0 + l31][hc]);
                qB1 = *reinterpret_cast<const bf16x8*>(&qs[32 + l31][hc]);
            }
            // V^T A-frags per 16-tk chunk: row = d = l31 (<8 real), k = tk 16c+8*half..+7
            bf16x8 vA0 = bzero8(), vA1 = bzero8(), vA2 = bzero8(), vA3 = bzero8();
            if (l31 < 8) {
                vA0 = *reinterpret_cast<const bf16x8*>(&vt[hc + l31][ 0 + 8 * half]);
                vA1 = *reinterpret_cast<const bf16x8*>(&vt[hc + l31][16 + 8 * half]);
                vA2 = *reinterpret_cast<const bf16x8*>(&vt[hc + l31][32 + 8 * half]);
                vA3 = *reinterpret_cast<const bf16x8*>(&vt[hc + l31][48 + 8 * half]);
            }

            f32x16 zc16;
            #pragma unroll
            for (int r = 0; r < 16; ++r) zc16[r] = 0.f;

            // ================= tq-tile 0 (tq = l31; tk-tile 0 only, causal) =================
            {
                f32x16 S = __builtin_amdgcn_mfma_f32_32x32x16_bf16(kA0, qB0, zc16, 0, 0, 0);
                #pragma unroll
                for (int r = 0; r < 16; ++r) {
                    const int tk = (r & 3) + 8 * (r >> 2) + 4 * half;
                    S[r] = (tk > l31) ? -3.0e38f : S[r];
                }
                float mx = S[0];
                #pragma unroll
                for (int r = 1; r < 16; ++r) mx = fmaxf(mx, S[r]);
                mx = fmaxf(mx, __shfl_xor(mx, 32));
                float sum = 0.f;
                #pragma unroll
                for (int r = 0; r < 16; ++r) { const float p = EXP2F(S[r] - mx); S[r] = p; sum += p; }
                sum += __shfl_xor(sum, 32);

                // pack P (bf16 pairs): u[i] holds tk {2i,2i+1} of this half's tk-quads
                unsigned u[8];
                #pragma unroll
                for (int i = 0; i < 8; ++i) {
                    union { __bf16 h[2]; unsigned w; } cv;
                    cv.h[0] = (__bf16)S[2 * i]; cv.h[1] = (__bf16)S[2 * i + 1];
                    u[i] = cv.w;
                }
                f32x16 O = zc16;
                #pragma unroll
                for (int c = 0; c < 2; ++c) {
                    const unsigned x0 = __shfl_xor(u[4 * c + 0], 32);
                    const unsigned x1 = __shfl_xor(u[4 * c + 1], 32);
                    const unsigned x2 = __shfl_xor(u[4 * c + 2], 32);
                    const unsigned x3 = __shfl_xor(u[4 * c + 3], 32);
                    union { unsigned w[4]; bf16x8 v; } bw;
                    bw.w[0] = half ? x2 : u[4 * c + 0];
                    bw.w[1] = half ? x3 : u[4 * c + 1];
                    bw.w[2] = half ? u[4 * c + 2] : x0;
                    bw.w[3] = half ? u[4 * c + 3] : x1;
                    O = __builtin_amdgcn_mfma_f32_32x32x16_bf16(c ? vA1 : vA0, bw.v, O, 0, 0, 0);
                }
                // out^T C: col = tq = l31, rows 0..3 = d 4*half..+3 (rows>=8 hit zero V rows)
                const float inv = RCPF(sum);
                bf16x4 ov;
                #pragma unroll
                for (int r = 0; r < 4; ++r) ov[r] = (__bf16)(O[r] * inv);
                *reinterpret_cast<bf16x4*>(&qs[l31][hc + 4 * half]) = ov;
            }

            // ================= tq-tile 1 (tq = 32+l31; tk-tiles 0 and 1) =================
            {
                f32x16 Sa = __builtin_amdgcn_mfma_f32_32x32x16_bf16(kA0, qB1, zc16, 0, 0, 0);
                f32x16 Sb = __builtin_amdgcn_mfma_f32_32x32x16_bf16(kA1, qB1, zc16, 0, 0, 0);
                #pragma unroll
                for (int r = 0; r < 16; ++r) {   // mask only the diagonal tile (tk 32..63)
                    const int tk = (r & 3) + 8 * (r >> 2) + 4 * half;
                    Sb[r] = (tk > l31) ? -3.0e38f : Sb[r];
                }
                float mx = Sa[0];
                #pragma unroll
                for (int r = 1; r < 16; ++r) mx = fmaxf(mx, Sa[r]);
                #pragma unroll
                for (int r = 0; r < 16; ++r) mx = fmaxf(mx, Sb[r]);
                mx = fmaxf(mx, __shfl_xor(mx, 32));
                float sum = 0.f;
                #pragma unroll
                for (int r = 0; r < 16; ++r) { const float p = EXP2F(Sa[r] - mx); Sa[r] = p; sum += p; }
                #pragma unroll
                for (int r = 0; r < 16; ++r) { const float p = EXP2F(Sb[r] - mx); Sb[r] = p; sum += p; }
                sum += __shfl_xor(sum, 32);

                unsigned ua[8], ub[8];
                #pragma unroll
                for (int i = 0; i < 8; ++i) {
                    union { __bf16 h[2]; unsigned w; } cv;
                    cv.h[0] = (__bf16)Sa[2 * i]; cv.h[1] = (__bf16)Sa[2 * i + 1];
                    ua[i] = cv.w;
                }
                #pragma unroll
                for (int i = 0; i < 8; ++i) {
                    union { __bf16 h[2]; unsigned w; } cv;
                    cv.h[0] = (__bf16)Sb[2 * i]; cv.h[1] = (__bf16)Sb[2 * i + 1];
                    ub[i] = cv.w;
                }
                f32x16 O = zc16;
                #pragma unroll
                for (int c = 0; c < 4; ++c) {
                    const unsigned* uu = (c < 2) ? ua : ub;
                    const int c2 = c & 1;
                    const unsigned x0 = __shfl_xor(uu[4 * c2 + 0], 32);
                    const unsigned x1 = __shfl_xor(uu[4 * c2 + 1], 32);
                    const unsigned x2 = __shfl_xor(uu[4 * c2 + 2], 32);
                    const unsigned x3 = __shfl_xor(uu[4 * c2 + 3], 32);
                    union { unsigned w[4]; bf16x8 v; } bw;
                    bw.w[0] = half ? x2 : uu[4 * c2 + 0];
                    bw.w[1] = half ? x3 : uu[4 * c2 + 1];
                    bw.w[2] = half ? uu[4 * c2 + 2] : x0;
                    bw.w[3] = half ? uu[4 * c2 + 3] : x1;
                    const bf16x8 vA = (c == 0) ? vA0 : (c == 1) ? vA1 : (c == 2) ? vA2 : vA3;
                    O = __builtin_amdgcn_mfma_f32_32x32x16_bf16(vA, bw.v, O, 0, 0, 0);
                }
                const float inv = RCPF(sum);
                bf16x4 ov;
                #pragma unroll
                for (int r = 0; r < 4; ++r) ov[r] = (__bf16)(O[r] * inv);
                *reinterpret_cast<bf16x4*>(&qs[32 + l31][hc + 4 * half]) = ov;
            }
        }
    }
    __syncthreads();

    // ---------------- Phase 4a: hidden = gelu(attn_out @ W15^T + b15) -> ks (swapped) -------
    // D[feat=n0+4q+r][t=m0+cl]: b64 write per tile. B-frag = attn_out rows (qs).
    {
        const bf16x8 h0 = *reinterpret_cast<const bf16x8*>(&qs[m0 + cl][kb]);
        const bf16x8 h1 = *reinterpret_cast<const bf16x8*>(&qs[m0 + cl][32 + kb]);
        #pragma unroll
        for (int nt = 0; nt < 4; ++nt) {
            const int n0 = nt * 16;
            f32x4 acc = {0.f, 0.f, 0.f, 0.f};
            const bf16x8 w0 = *reinterpret_cast<const bf16x8*>(&W15b[(n0 + cl) * Dn + kb]);
            acc = __builtin_amdgcn_mfma_f32_16x16x32_bf16(w0, h0, acc, 0, 0, 0);
            const bf16x8 w1 = *reinterpret_cast<const bf16x8*>(&W15b[(n0 + cl) * Dn + 32 + kb]);
            acc = __builtin_amdgcn_mfma_f32_16x16x32_bf16(w1, h1, acc, 0, 0, 0);
            const float4 bs = *reinterpret_cast<const float4*>(&b15[n0 + 4 * quad]);
            bf16x4 pk;
            pk[0] = (__bf16)geluf(acc[0] + bs.x);
            pk[1] = (__bf16)geluf(acc[1] + bs.y);
            pk[2] = (__bf16)geluf(acc[2] + bs.z);
            pk[3] = (__bf16)geluf(acc[3] + bs.w);
            *reinterpret_cast<bf16x4*>(&ks[m0 + cl][n0 + 4 * quad]) = pk;
        }
    }
    // No barrier: phase 4b reads only this wave's 16 rows of ks (same-wave DS in-order).

    // ---------------- Phase 4b: out = hidden @ W16^T + b16 -> global fp32 (swapped) ---------
    // D[feat=n0+4q+r][t=m0+cl]: one dwordx4 global store per tile.
    {
        const bf16x8 h0 = *reinterpret_cast<const bf16x8*>(&ks[m0 + cl][kb]);
        const bf16x8 h1 = *reinterpret_cast<const bf16x8*>(&ks[m0 + cl][32 + kb]);
        const size_t ob = (((size_t)(b * Tn + m0 + cl)) * Nn + n) * (size_t)Dn;
        #pragma unroll
        for (int nt = 0; nt < 4; ++nt) {
            const int n0 = nt * 16;
            f32x4 acc = {0.f, 0.f, 0.f, 0.f};
            const bf16x8 w0 = *reinterpret_cast<const bf16x8*>(&W16b[(n0 + cl) * Dn + kb]);
            acc = __builtin_amdgcn_mfma_f32_16x16x32_bf16(w0, h0, acc, 0, 0, 0);
            const bf16x8 w1 = *reinterpret_cast<const bf16x8*>(&W16b[(n0 + cl) * Dn + 32 + kb]);
            acc = __builtin_amdgcn_mfma_f32_16x16x32_bf16(w1, h1, acc, 0, 0, 0);
            const float4 bs = *reinterpret_cast<const float4*>(&b16[n0 + 4 * quad]);
            float4 ov;
            ov.x = acc[0] + bs.x;
            ov.y = acc[1] + bs.y;
            ov.z = acc[2] + bs.z;
            ov.w = acc[3] + bs.w;
            *reinterpret_cast<float4*>(&Out[ob + n0 + 4 * quad]) = ov;
        }
    }
}

extern "C" void kernel_launch(void* const* d_in, const int* in_sizes, int n_in,
                              void* d_out, int out_size, void* d_ws, size_t ws_size,
                              hipStream_t stream)
{
    (void)in_sizes; (void)n_in; (void)out_size; (void)ws_size;
    const float* X   = (const float*)d_in[0];
    const float* STE = (const float*)d_in[1];
    const float* W12 = (const float*)d_in[2];
    const float* b12 = (const float*)d_in[3];
    const float* W13 = (const float*)d_in[4];
    const float* b13 = (const float*)d_in[5];
    const float* W14 = (const float*)d_in[6];
    const float* b14 = (const float*)d_in[7];
    const float* W15 = (const float*)d_in[8];
    const float* b15 = (const float*)d_in[9];
    const float* W16 = (const float*)d_in[10];
    const float* b16 = (const float*)d_in[11];
    float* Out = (float*)d_out;
    __bf16* ws = (__bf16*)d_ws;   // needs 65,536 B

    hipLaunchKernelGGL(convert_weights, dim3(128), dim3(256), 0, stream,
                       W12, W13, W14, W15, W16, ws);
    hipLaunchKernelGGL(tam_fused, dim3(Bn * Nn), dim3(256), 0, stream,
                       X, STE, b12, b13, b14, b15, b16, ws, Out);
}